// Round 5
// baseline (323.761 us; speedup 1.0000x reference)
//
#include <hip/hip_runtime.h>

// ForwardKinematics: B=128, T=1024, J=24, SMPL skeleton.
// positions out: (B,T,24,3) fp32 ; rotations out: (B,T,24,3,3) fp32
// d_out = positions || rotations (flat, return order).
//
// Round 4 (resubmit; round-4 bench was a broker timeout, no data):
// round-3 counters: traffic near-ideal (107+173 MB) but BW only
// 2.24 TB/s -> latency-bound. Cause: 12 __syncthreads per thread, each
// forcing a vmcnt(0) drain (compiler emits full waitcnt before s_barrier),
// so no load ever stays in flight across a staging phase. Fix: wave-local
// staging (each wave stages its own 64 chains, cooperative stores within
// the wave) -> ZERO barriers, loads pipeline across all 6 groups.

#define FK_T 1024
#define FK_J 24
#define FK_N (128 * 1024)           // 131072 chains

constexpr int kPar[FK_J] = {-1, 0, 0, 0, 1, 2, 3, 4, 5, 6, 7, 8,
                            9, 9, 9, 12, 13, 14, 16, 17, 18, 19, 20, 21};

__global__ __launch_bounds__(256, 2) void fk_kernel(
    const float* __restrict__ rot,   // (B,T,24,3,3)
    const float* __restrict__ pos,   // (B,T,3)
    const float* __restrict__ off,   // (B,24,3)
    float* __restrict__ opos,        // (B,T,24,3)
    float* __restrict__ orot)        // (B,T,24,3,3)
{
    // Per-wave staging region: 64 chains x 13 float4 (9 rot + 3 pos + 1 pad).
    // Wave-local => no __syncthreads needed anywhere (DS is in-order per wave,
    // write->read ordering via compiler-inserted lgkmcnt).
    __shared__ float4 sb[256 * 13];  // 53,248 B

    const unsigned t    = threadIdx.x;
    const unsigned lane = t & 63u;
    const unsigned wv   = t >> 6;
    const unsigned bc   = blockIdx.x * 256u;   // block's base chain
    const unsigned n    = bc + t;              // this thread's chain (= b*T + t')
    const unsigned b    = bc >> 10;            // uniform across block
    const float* __restrict__ offb = off + b * (FK_J * 3);

    const float4* __restrict__ rin = reinterpret_cast<const float4*>(rot) + (size_t)n * 54;

    const unsigned wbc = bc + wv * 64u;        // wave's base chain
    float4* __restrict__ rout_w = reinterpret_cast<float4*>(orot) + (size_t)wbc * 54;
    float4* __restrict__ pout_w = reinterpret_cast<float4*>(opos) + (size_t)wbc * 18;
    float4* __restrict__ sw = sb + wv * (64u * 13u);

    // Register-resident chain state (static indices after full unroll).
    float G[FK_J][9];
    float J[FK_J][3];

    const float p0 = pos[n * 3 + 0];
    const float p1 = pos[n * 3 + 1];
    const float p2 = pos[n * 3 + 2];

    #pragma unroll
    for (int g = 0; g < 6; ++g) {
        // ---- per-thread input: 9 consecutive float4 (144B). With no barriers
        // in the loop, later groups' loads can issue while this group stages.
        float fr[36];
        #pragma unroll
        for (int s = 0; s < 9; ++s) {
            float4 v = rin[g * 9 + s];
            fr[4 * s + 0] = v.x; fr[4 * s + 1] = v.y;
            fr[4 * s + 2] = v.z; fr[4 * s + 3] = v.w;
        }

        // ---- compute 4 joints of this group
        float go[36];   // rotations out (global layout order)
        float jo[12];   // positions out (global layout order)
        #pragma unroll
        for (int u = 0; u < 4; ++u) {
            const int i = 4 * g + u;
            if (i == 0) {
                #pragma unroll
                for (int k = 0; k < 9; ++k) G[0][k] = fr[k];
                J[0][0] = p0; J[0][1] = p1; J[0][2] = p2;
            } else {
                const int p = kPar[i];   // constant after unroll
                const float o0 = offb[i * 3 + 0];
                const float o1 = offb[i * 3 + 1];
                const float o2 = offb[i * 3 + 2];
                #pragma unroll
                for (int r = 0; r < 3; ++r) {
                    const float a0 = G[p][3 * r + 0];
                    const float a1 = G[p][3 * r + 1];
                    const float a2 = G[p][3 * r + 2];
                    G[i][3 * r + 0] = a0 * fr[9 * u + 0] + a1 * fr[9 * u + 3] + a2 * fr[9 * u + 6];
                    G[i][3 * r + 1] = a0 * fr[9 * u + 1] + a1 * fr[9 * u + 4] + a2 * fr[9 * u + 7];
                    G[i][3 * r + 2] = a0 * fr[9 * u + 2] + a1 * fr[9 * u + 5] + a2 * fr[9 * u + 8];
                    J[i][r] = a0 * o0 + a1 * o1 + a2 * o2 + J[p][r];
                }
            }
            #pragma unroll
            for (int k = 0; k < 9; ++k) go[9 * u + k] = G[i][k];
            #pragma unroll
            for (int k = 0; k < 3; ++k) jo[3 * u + k] = J[i][k];
        }

        // ---- stage this group's outputs in the wave's LDS region
        #pragma unroll
        for (int j = 0; j < 9; ++j)
            sw[lane * 13 + j] = make_float4(go[4 * j + 0], go[4 * j + 1],
                                            go[4 * j + 2], go[4 * j + 3]);
        #pragma unroll
        for (int v = 0; v < 3; ++v)
            sw[lane * 13 + 9 + v] = make_float4(jo[4 * v + 0], jo[4 * v + 1],
                                                jo[4 * v + 2], jo[4 * v + 3]);

        // ---- cooperative stores within the wave: lane-consecutive addresses.
        // rotations: 64 chains x 9 float4 = 576 float4, 9 per lane
        #pragma unroll
        for (int k = 0; k < 9; ++k) {
            const unsigned r = (unsigned)k * 64u + lane;  // 0..575
            const unsigned c = r / 9u;                    // magic-mul div
            const unsigned s = r - c * 9u;
            rout_w[c * 54 + (unsigned)g * 9 + s] = sw[c * 13 + s];
        }
        // positions: 64 chains x 3 float4 = 192 float4, 3 per lane
        #pragma unroll
        for (int k = 0; k < 3; ++k) {
            const unsigned q = (unsigned)k * 64u + lane;  // 0..191
            const unsigned c = q / 3u;
            const unsigned v = q - c * 3u;
            pout_w[c * 18 + (unsigned)g * 3 + v] = sw[c * 13 + 9 + v];
        }
    }
}

extern "C" void kernel_launch(void* const* d_in, const int* in_sizes, int n_in,
                              void* d_out, int out_size, void* d_ws, size_t ws_size,
                              hipStream_t stream) {
    const float* rot = (const float*)d_in[0];   // (B,T,24,3,3)
    const float* pos = (const float*)d_in[1];   // (B,T,3)
    const float* off = (const float*)d_in[2];   // (B,24,3)
    // d_in[3] = parents: structural constant (SMPL tree), folded into kPar.

    float* opos = (float*)d_out;                                    // (B,T,24,3)
    float* orot = (float*)d_out + (size_t)FK_N * FK_J * 3;          // (B,T,24,3,3)

    const int threads = 256;
    const int blocks  = FK_N / threads;   // 512
    fk_kernel<<<blocks, threads, 0, stream>>>(rot, pos, off, opos, orot);
}